// Round 2
// baseline (178.995 us; speedup 1.0000x reference)
//
#include <hip/hip_runtime.h>

using bf16 = __bf16;
typedef __bf16 bf16x8 __attribute__((ext_vector_type(8)));
typedef __bf16 bf16x4 __attribute__((ext_vector_type(4)));
typedef float  f32x4  __attribute__((ext_vector_type(4)));

#define MFMA16(a, b, c) __builtin_amdgcn_mfma_f32_16x16x32_bf16((a), (b), (c), 0, 0, 0)

static constexpr int S = 2048, E = 1024;
static constexpr float CSCALE = 0.18033688011112042f;  // 1/sqrt(64) * log2(e)

__device__ __forceinline__ void gld16(const bf16* g, bf16* l) {
    __builtin_amdgcn_global_load_lds((const __attribute__((address_space(1))) unsigned*)g,
                                     (__attribute__((address_space(3))) unsigned*)l, 16, 0, 0);
}

// ---------------- fused prep: cvt(hs) + transpose-cvt(w0) + transpose-cvt(w1) ----------------
__global__ __launch_bounds__(256) void k_prep(const float* __restrict__ hs, const float* __restrict__ w0,
                                              const float* __restrict__ w1, bf16* __restrict__ A0,
                                              bf16* __restrict__ Wt0, bf16* __restrict__ Wt1) {
    __shared__ float tile[32][33];
    const int bx = blockIdx.x;
    if (bx < 4096) {
        int i = (bx * 256 + threadIdx.x) * 4;
        float4 v = *(const float4*)(hs + i);
        bf16x4 o = { (bf16)v.x, (bf16)v.y, (bf16)v.z, (bf16)v.w };
        *(bf16x4*)(A0 + i) = o;
        return;
    }
    const float* in;
    bf16* outp;
    int K, N, nb, kb;
    if (bx < 4096 + 3072) {
        int j = bx - 4096; in = w0; outp = Wt0; K = 1024; N = 3072; nb = j % 96; kb = j / 96;
    } else {
        int j = bx - 7168; in = w1; outp = Wt1; K = 1024; N = 1024; nb = j % 32; kb = j / 32;
    }
    const int bxx = nb * 32, byy = kb * 32;
    const int tx = threadIdx.x & 31, ty = threadIdx.x >> 5;
#pragma unroll
    for (int i = 0; i < 32; i += 8)
        tile[ty + i][tx] = in[(long)(byy + ty + i) * N + bxx + tx];
    __syncthreads();
#pragma unroll
    for (int i = 0; i < 32; i += 8)
        outp[(long)(bxx + ty + i) * K + byy + tx] = (bf16)tile[tx][ty + i];
}

// ---------------- QKV GEMM: 128x192 tile, 512 blocks (2/CU), 6 waves (2Mx3N, 64x64/wave),
// BK=32, 3-slot LDS ring (60KB), counted vmcnt + setprio; cross-block overlap is the lever ----------------
__global__ __launch_bounds__(384, 3) void k_gemm_qkv(const bf16* __restrict__ A, const bf16* __restrict__ Bt,
                                                     const float* __restrict__ bias, bf16* __restrict__ Qs,
                                                     bf16* __restrict__ Kf, bf16* __restrict__ Vf, int Kk) {
    __shared__ __align__(16) char smem[61440];
    bf16* sA = (bf16*)smem;                // 3 slots x [128 rows][32 k]  (8192 B / slot)
    bf16* sB = (bf16*)(smem + 24576);      // 3 slots x [192 rows][32 k]  (12288 B / slot)

    const int NT = Kk >> 5;                // 32 K-tiles of BK=32

    // XCD-bijective swizzle (512 % 8 == 0): 64 consecutive sids per XCD; bm varies fastest
    const int bid = blockIdx.x;
    const int sid = (bid & 7) * 64 + (bid >> 3);
    const long bm = (long)(sid & 31) * 128;
    const long bn = (long)(sid >> 5) * 192;

    const int tid = threadIdx.x;
    const int w = tid >> 6, lane = tid & 63;
    const int col = lane & 15, quad = lane >> 4;
    const int wc = w % 3, wr = w / 3;      // wave tile: rows wr*64, cols wc*64
    const int wrow = wr * 64, wcol = wc * 64;

    // staging: 20 wave-chunks/tile (A: 0..7 = 128x32, B: 8..19 = 192x32), chunk c -> wave (c%6)
    // waves 0-1 carry 4 chunks, waves 2-5 carry 3.
    const int nch = (w < 2) ? 4 : 3;
    const bf16* gsrc[4];
    bf16* ldst[4];
    int sstep[4];
#pragma unroll
    for (int j = 0; j < 4; ++j) {
        const int c = w + 6 * j;
        const bool a = (c < 8);
        const int cl = a ? c : (c - 8);
        const int r = cl * 16 + (lane >> 2);
        const int kc = (lane & 3) ^ ((r >> 1) & 3);     // source pre-swizzle; LDS stays linear
        gsrc[j] = (a ? A + (bm + r) * Kk : Bt + (bn + r) * Kk) + kc * 8;
        ldst[j] = (a ? sA : sB) + r * 32 + (lane & 3) * 8;
        sstep[j] = a ? 4096 : 6144;                      // slot stride in elements
    }

    f32x4 acc[4][4] = {};

    // prologue: stage tiles 0,1 into slots 0,1; wait for tile 0 (keep tile 1 in flight)
#pragma unroll
    for (int tt = 0; tt < 2; ++tt)
#pragma unroll
        for (int j = 0; j < 4; ++j)
            if (j < nch) gld16(gsrc[j] + tt * 32, ldst[j] + tt * sstep[j]);
    if (w < 2) asm volatile("s_waitcnt vmcnt(4)" ::: "memory");
    else       asm volatile("s_waitcnt vmcnt(3)" ::: "memory");
    __builtin_amdgcn_s_barrier();

    int slot = 0, wslot = 2;               // compute slot = t%3 ; stage slot = (t+2)%3
#pragma unroll 1
    for (int t = 0; t < NT; ++t) {
        const bf16* sAs = sA + slot * 4096;
        const bf16* sBs = sB + slot * 6144;

        // stage tile t+2 into the slot tile t-1 just freed
        if (t + 2 < NT) {
#pragma unroll
            for (int j = 0; j < 4; ++j)
                if (j < nch) gld16(gsrc[j] + (t + 2) * 32, ldst[j] + wslot * sstep[j]);
        }

        // fragment loads (slot t: guaranteed complete by previous iter's vmcnt+barrier)
        bf16x8 af[4], bfr[4];
#pragma unroll
        for (int mt = 0; mt < 4; ++mt) {
            const int row = wrow + mt * 16 + col;
            af[mt] = *(const bf16x8*)(sAs + row * 32 + ((quad ^ ((row >> 1) & 3)) * 8));
        }
#pragma unroll
        for (int nt = 0; nt < 4; ++nt) {
            const int row = wcol + nt * 16 + col;
            bfr[nt] = *(const bf16x8*)(sBs + row * 32 + ((quad ^ ((row >> 1) & 3)) * 8));
        }
        __builtin_amdgcn_s_barrier();
        __builtin_amdgcn_s_setprio(1);
#pragma unroll
        for (int mt = 0; mt < 4; ++mt)
#pragma unroll
            for (int nt = 0; nt < 4; ++nt)
                acc[mt][nt] = MFMA16(af[mt], bfr[nt], acc[mt][nt]);
        __builtin_amdgcn_s_setprio(0);
        // drain tile t+1's loads; keep tile t+2 in flight (counted, never 0 mid-loop)
        if (t < NT - 2) {
            if (w < 2) asm volatile("s_waitcnt vmcnt(4)" ::: "memory");
            else       asm volatile("s_waitcnt vmcnt(3)" ::: "memory");
        } else {
            asm volatile("s_waitcnt vmcnt(0)" ::: "memory");
        }
        __builtin_amdgcn_s_barrier();

        slot = (slot == 2) ? 0 : slot + 1;
        wslot = (wslot == 2) ? 0 : wslot + 1;
    }

    // ---------------- epilogue (fully per-wave private; each wave's 64 cols = one head/segment) ----------------
    const long gc0 = bn + wcol;
    const int seg = (int)(gc0 >> 10);      // 0: Q, 1: K, 2: V
    float bv[4];
#pragma unroll
    for (int nt = 0; nt < 4; ++nt) bv[nt] = bias[gc0 + nt * 16 + col];

    if (seg == 0) {
#pragma unroll
        for (int nt = 0; nt < 4; ++nt) {
            const long gc = gc0 + nt * 16 + col;
#pragma unroll
            for (int mt = 0; mt < 4; ++mt) {
                const long gr = bm + wrow + mt * 16 + quad * 4;
#pragma unroll
                for (int r = 0; r < 4; ++r)
                    Qs[(gr + r) * 1024 + gc] = (bf16)((acc[mt][nt][r] + bv[nt]) * CSCALE);
            }
        }
        return;
    }

    // per-wave 64x72 LDS scratch overlaying the (now dead) staging buffers
    bf16* myT = (bf16*)smem + w * 4608;
    const int bmi = (int)bm;
    const int b = bmi >> 11;
    const int ktw = ((bmi & 2047) >> 6) + wr;           // wave's 64-row seq tile
    const int head = (int)((gc0 & 1023) >> 6);
    const int bh = b * 16 + head;

    if (seg == 1) {
        // K: myT[seq][d] row-major, then fragment reads [16 seq][32 d]
#pragma unroll
        for (int mt = 0; mt < 4; ++mt)
#pragma unroll
            for (int nt = 0; nt < 4; ++nt)
#pragma unroll
                for (int r = 0; r < 4; ++r)
                    myT[(mt * 16 + quad * 4 + r) * 72 + nt * 16 + col] = (bf16)(acc[mt][nt][r] + bv[nt]);
#pragma unroll
        for (int mtp = 0; mtp < 4; ++mtp)
#pragma unroll
            for (int half = 0; half < 2; ++half) {
                bf16x8 ch = *(const bf16x8*)(myT + (mtp * 16 + col) * 72 + half * 32 + quad * 8);
                const long chunk = ((long)(bh * 32 + ktw) * 8 + mtp * 2 + half) * 64 + lane;
                *(bf16x8*)(Kf + chunk * 8) = ch;
            }
    } else {
        // V: myT[d][seq] (vectorized along seq), then fragment reads [16 d][32 seq]
#pragma unroll
        for (int nt = 0; nt < 4; ++nt)
#pragma unroll
            for (int mt = 0; mt < 4; ++mt) {
                bf16x4 pk = { (bf16)(acc[mt][nt][0] + bv[nt]), (bf16)(acc[mt][nt][1] + bv[nt]),
                              (bf16)(acc[mt][nt][2] + bv[nt]), (bf16)(acc[mt][nt][3] + bv[nt]) };
                *(bf16x4*)(myT + (nt * 16 + col) * 72 + mt * 16 + quad * 4) = pk;
            }
#pragma unroll
        for (int dt = 0; dt < 4; ++dt)
#pragma unroll
            for (int ks = 0; ks < 2; ++ks) {
                bf16x8 ch = *(const bf16x8*)(myT + (dt * 16 + col) * 72 + ks * 32 + quad * 8);
                const long chunk = ((long)(bh * 32 + ktw) * 8 + dt * 2 + ks) * 64 + lane;
                *(bf16x8*)(Vf + chunk * 8) = ch;
            }
    }
}

// ---------------- bf16 GEMM 64x128 tile, BK=64, XOR-swizzled (proj) ----------------
__global__ __launch_bounds__(256) void k_gemm_bt64(const bf16* __restrict__ A, const bf16* __restrict__ Bt,
                                                    const float* __restrict__ bias, float* __restrict__ Cout,
                                                    int Mm, int Nn, int Kk) {
    const int bm = blockIdx.x * 64;
    const int bn = blockIdx.y * 128;
    const int tid = threadIdx.x;
    const int w = tid >> 6, lane = tid & 63;
    const int wm = (w >> 1) * 32, wn = (w & 1) * 64;
    const int col = lane & 15, quad = lane >> 4;

    __shared__ bf16 sA[64 * 64];
    __shared__ bf16 sB[128 * 64];

    const bf16* pA[2]; bf16* lA[2];
#pragma unroll
    for (int i = 0; i < 2; i++) {
        const int c = i * 256 + w * 64 + lane;
        const int r = c >> 3, sl = (c & 7) ^ (r & 7);
        pA[i] = A + (long)(bm + r) * Kk + sl * 8;
        lA[i] = sA + i * 2048 + w * 512;
    }
    const bf16* pB[4]; bf16* lB[4];
#pragma unroll
    for (int i = 0; i < 4; i++) {
        const int c = i * 256 + w * 64 + lane;
        const int r = c >> 3, sl = (c & 7) ^ (r & 7);
        pB[i] = Bt + (long)(bn + r) * Kk + sl * 8;
        lB[i] = sB + i * 2048 + w * 512;
    }

    f32x4 acc[2][4] = {};

    for (int k0 = 0; k0 < Kk; k0 += 64) {
        __syncthreads();
#pragma unroll
        for (int i = 0; i < 2; i++) gld16(pA[i] + k0, lA[i]);
#pragma unroll
        for (int i = 0; i < 4; i++) gld16(pB[i] + k0, lB[i]);
        __syncthreads();
#pragma unroll
        for (int h = 0; h < 2; h++) {
            bf16x8 af[2], bfr[4];
#pragma unroll
            for (int mt = 0; mt < 2; mt++) {
                const int row = wm + mt * 16 + col;
                af[mt] = *(const bf16x8*)(sA + row * 64 + (((h * 4 + quad) ^ (col & 7)) * 8));
            }
#pragma unroll
            for (int nt = 0; nt < 4; nt++) {
                const int row = wn + nt * 16 + col;
                bfr[nt] = *(const bf16x8*)(sB + row * 64 + (((h * 4 + quad) ^ (col & 7)) * 8));
            }
#pragma unroll
            for (int mt = 0; mt < 2; mt++)
#pragma unroll
                for (int nt = 0; nt < 4; nt++)
                    acc[mt][nt] = MFMA16(af[mt], bfr[nt], acc[mt][nt]);
        }
    }

#pragma unroll
    for (int mt = 0; mt < 2; mt++) {
        const int gr = bm + wm + mt * 16 + quad * 4;
#pragma unroll
        for (int nt = 0; nt < 4; nt++) {
            const int gc = bn + wn + nt * 16 + col;
            const float bv = bias[gc];
#pragma unroll
            for (int r = 0; r < 4; r++)
                Cout[(long)(gr + r) * Nn + gc] = acc[mt][nt][r] + bv;
        }
    }
}

// ---------------- causal flash attention: kt-split uniform waves + flash-decode merge ----------------
__global__ __launch_bounds__(128) void k_attn(const bf16* __restrict__ Qs, const bf16* __restrict__ Kf,
                                              const bf16* __restrict__ Vf, bf16* __restrict__ out) {
    const int bh = blockIdx.x & 31;
    const int tp = blockIdx.x >> 5;           // tile pair 0..31
    const int b = bh >> 4, h = bh & 15;
    const int tid = threadIdx.x;
    const int w = tid >> 6, lane = tid & 63;
    const int col = lane & 15, quad = lane >> 4;

    __shared__ bf16 sP[2][32 * 72];
    __shared__ float M[2][64][36];            // [sel][lane][0..31 O | 32 m0 33 l0 34 m1 35 l1]
    bf16* pw = sP[w];

    const bf16* kfb = Kf + ((long)bh << 17) + lane * 8;
    const bf16* vfb = Vf + ((long)bh << 17) + lane * 8;

#pragma unroll 1
    for (int sel = 0; sel < 2; sel++) {
        const int t = sel ? 63 - tp : tp;
        const int q0 = t * 32;
        const int nkt = (t >> 1) + 1;
        const int kA = nkt >> 1;
        const int kbeg = w ? kA : 0;
        const int kend = w ? nkt : kA;

        bf16x8 bq[2][2];
#pragma unroll
        for (int qg = 0; qg < 2; qg++) {
            const bf16* qp = Qs + (long)(b * S + q0 + qg * 16 + col) * E + h * 64 + quad * 8;
            bq[qg][0] = *(const bf16x8*)(qp);
            bq[qg][1] = *(const bf16x8*)(qp + 32);
        }
        float m_[2] = { -1e30f, -1e30f }, l_[2] = { 0.f, 0.f };
        f32x4 o[2][4] = {};

#pragma unroll 1
        for (int kt = kbeg; kt < kend; kt++) {
            bf16x8 kfr[4][2], vfr[4][2];
#pragma unroll
            for (int mt = 0; mt < 4; mt++)
#pragma unroll
                for (int half = 0; half < 2; half++)
                    kfr[mt][half] = *(const bf16x8*)(kfb + ((long)(kt * 8 + mt * 2 + half) << 9));
#pragma unroll
            for (int dt = 0; dt < 4; dt++)
#pragma unroll
                for (int ks = 0; ks < 2; ks++)
                    vfr[dt][ks] = *(const bf16x8*)(vfb + ((long)(kt * 8 + dt * 2 + ks) << 9));

            f32x4 s[2][4];
#pragma unroll
            for (int mt = 0; mt < 4; mt++)
#pragma unroll
                for (int qg = 0; qg < 2; qg++) {
                    f32x4 z = {};
                    z = MFMA16(kfr[mt][0], bq[qg][0], z);
                    z = MFMA16(kfr[mt][1], bq[qg][1], z);
                    s[qg][mt] = z;
                }
            if (kt == nkt - 1) {  // diagonal tile (always in wave 1's range)
#pragma unroll
                for (int qg = 0; qg < 2; qg++) {
                    const int qrow = q0 + qg * 16 + col;
#pragma unroll
                    for (int mt = 0; mt < 4; mt++)
#pragma unroll
                        for (int r = 0; r < 4; r++)
                            if (kt * 64 + mt * 16 + quad * 4 + r > qrow) s[qg][mt][r] = -1e30f;
                }
            }
#pragma unroll
            for (int qg = 0; qg < 2; qg++) {
                float cm = -1e30f;
#pragma unroll
                for (int mt = 0; mt < 4; mt++)
#pragma unroll
                    for (int r = 0; r < 4; r++) cm = fmaxf(cm, s[qg][mt][r]);
                cm = fmaxf(cm, __shfl_xor(cm, 16));
                cm = fmaxf(cm, __shfl_xor(cm, 32));
                const float mnew = fmaxf(m_[qg], cm);
                const float alpha = __builtin_amdgcn_exp2f(m_[qg] - mnew);
                m_[qg] = mnew;
                float rs = 0.f;
#pragma unroll
                for (int mt = 0; mt < 4; mt++)
#pragma unroll
                    for (int r = 0; r < 4; r++) {
                        float pe = __builtin_amdgcn_exp2f(s[qg][mt][r] - mnew);
                        s[qg][mt][r] = pe;
                        rs += pe;
                    }
                l_[qg] = l_[qg] * alpha + rs;
#pragma unroll
                for (int dt = 0; dt < 4; dt++)
#pragma unroll
                    for (int r = 0; r < 4; r++) o[qg][dt][r] *= alpha;
#pragma unroll
                for (int mt = 0; mt < 4; mt++) {
                    bf16x4 pk = { (bf16)s[qg][mt][0], (bf16)s[qg][mt][1],
                                  (bf16)s[qg][mt][2], (bf16)s[qg][mt][3] };
                    *(bf16x4*)(pw + (qg * 16 + col) * 72 + mt * 16 + quad * 4) = pk;
                }
            }
#pragma unroll
            for (int ks = 0; ks < 2; ks++) {
                bf16x8 ap[2];
#pragma unroll
                for (int qg = 0; qg < 2; qg++)
                    ap[qg] = *(const bf16x8*)(pw + (qg * 16 + col) * 72 + ks * 32 + quad * 8);
#pragma unroll
                for (int dt = 0; dt < 4; dt++)
#pragma unroll
                    for (int qg = 0; qg < 2; qg++)
                        o[qg][dt] = MFMA16(vfr[dt][ks], ap[qg], o[qg][dt]);
            }
        }

        // finish per-lane l reduction -> replicated row sums
#pragma unroll
        for (int qg = 0; qg < 2; qg++) {
            float lt = l_[qg];
            lt += __shfl_xor(lt, 16);
            lt += __shfl_xor(lt, 32);
            l_[qg] = lt;
        }

        if (w == 0) {  // publish lower-half partials
#pragma unroll
            for (int qg = 0; qg < 2; qg++) {
#pragma unroll
                for (int dt = 0; dt < 4; dt++)
                    *(f32x4*)&M[sel][lane][qg * 16 + dt * 4] = o[qg][dt];
                M[sel][lane][32 + qg * 2] = m_[qg];
                M[sel][lane][33 + qg * 2] = l_[qg];
            }
        }
        __syncthreads();
        if (w == 1) {  // merge + output
#pragma unroll
            for (int qg = 0; qg < 2; qg++) {
                const float m0 = M[sel][lane][32 + qg * 2];
                const float l0 = M[sel][lane][33 + qg * 2];
                const float mm = fmaxf(m0, m_[qg]);
                const float a0 = __builtin_amdgcn_exp2f(m0 - mm);
                const float a1 = __builtin_amdgcn_exp2f(m_[qg] - mm);
                const float li = 1.f / (l0 * a0 + l_[qg] * a1);
                bf16* op = out + (long)(b * S + q0 + qg * 16 + col) * E + h * 64 + quad * 4;
#pragma unroll
                for (int dt = 0; dt < 4; dt++) {
                    f32x4 o0 = *(const f32x4*)&M[sel][lane][qg * 16 + dt * 4];
                    bf16x4 ov;
#pragma unroll
                    for (int r = 0; r < 4; r++)
                        ov[r] = (bf16)((o0[r] * a0 + o[qg][dt][r] * a1) * li);
                    *(bf16x4*)(op + dt * 16) = ov;
                }
            }
        }
    }
}

extern "C" void kernel_launch(void* const* d_in, const int* in_sizes, int n_in,
                              void* d_out, int out_size, void* d_ws, size_t ws_size,
                              hipStream_t stream) {
    const float* hs = (const float*)d_in[0];   // [2,2048,1024]
    const float* w0 = (const float*)d_in[1];   // [1024,3072]
    const float* b0 = (const float*)d_in[2];   // [3072]
    const float* w1 = (const float*)d_in[3];   // [1024,1024]
    const float* b1 = (const float*)d_in[4];   // [1024]
    float* outp = (float*)d_out;               // [2,2048,1024] fp32

    char* ws = (char*)d_ws;
    bf16* A0    = (bf16*)(ws);                   // 8 MB
    bf16* Wt0   = (bf16*)(ws + 8388608);         // 6 MB
    bf16* Wt1   = (bf16*)(ws + 14680064);        // 2 MB
    bf16* Qs    = (bf16*)(ws + 16777216);        // 8 MB  [4096][1024] scaled Q
    bf16* Kf    = (bf16*)(ws + 25165824);        // 8 MB  fragment-linear K
    bf16* Vf    = (bf16*)(ws + 33554432);        // 8 MB  fragment-linear V^T
    bf16* attnO = (bf16*)(ws + 41943040);        // 8 MB

    k_prep<<<8192, 256, 0, stream>>>(hs, w0, w1, A0, Wt0, Wt1);
    k_gemm_qkv<<<512, 384, 0, stream>>>(A0, Wt0, b0, Qs, Kf, Vf, 1024);
    k_attn<<<1024, 128, 0, stream>>>(Qs, Kf, Vf, attnO);
    k_gemm_bt64<<<dim3(64, 8), 256, 0, stream>>>(attnO, Wt1, b1, outp, 4096, 1024, 1024);
}

// Round 5
// 175.194 us; speedup vs baseline: 1.0217x; 1.0217x over previous
//
#include <hip/hip_runtime.h>

using bf16 = __bf16;
typedef __bf16 bf16x8 __attribute__((ext_vector_type(8)));
typedef __bf16 bf16x4 __attribute__((ext_vector_type(4)));
typedef float  f32x4  __attribute__((ext_vector_type(4)));

#define MFMA16(a, b, c) __builtin_amdgcn_mfma_f32_16x16x32_bf16((a), (b), (c), 0, 0, 0)

static constexpr int S = 2048, E = 1024;
static constexpr float CSCALE = 0.18033688011112042f;  // 1/sqrt(64) * log2(e)

__device__ __forceinline__ void gld16(const bf16* g, bf16* l) {
    __builtin_amdgcn_global_load_lds((const __attribute__((address_space(1))) unsigned*)g,
                                     (__attribute__((address_space(3))) unsigned*)l, 16, 0, 0);
}

// 4 async fragment loads into registers (1 KB coalesced each); completion gated by manual vmcnt.
__device__ __forceinline__ void gload4(const bf16* p, bf16x8& r0, bf16x8& r1, bf16x8& r2, bf16x8& r3) {
    asm volatile("global_load_dwordx4 %0, %4, off\n\t"
                 "global_load_dwordx4 %1, %4, off offset:1024\n\t"
                 "global_load_dwordx4 %2, %4, off offset:2048\n\t"
                 "global_load_dwordx4 %3, %4, off offset:3072"
                 : "=&v"(r0), "=&v"(r1), "=&v"(r2), "=&v"(r3)
                 : "v"(p));
}

// ---------------- fused prep: cvt(hs) + fragment-linear-cvt(w0) + transpose-cvt(w1) ----------------
// Wt0 is written in MFMA B-fragment-linear order:
//   Wf[(((n>>6)*32 + (k>>5))*4 + ((n>>4)&3))*512 + ((k>>3)&3)*128 + (n&15)*8 + (k&7)] = w0[k][n]
__global__ __launch_bounds__(256) void k_prep(const float* __restrict__ hs, const float* __restrict__ w0,
                                              const float* __restrict__ w1, bf16* __restrict__ A0,
                                              bf16* __restrict__ Wt0, bf16* __restrict__ Wt1) {
    __shared__ float tile[32][33];
    const int bx = blockIdx.x;
    if (bx < 4096) {
        int i = (bx * 256 + threadIdx.x) * 4;
        float4 v = *(const float4*)(hs + i);
        bf16x4 o = { (bf16)v.x, (bf16)v.y, (bf16)v.z, (bf16)v.w };
        *(bf16x4*)(A0 + i) = o;
        return;
    }
    const float* in;
    bf16* outp;
    int K, N, nb, kb;
    bool frag;
    if (bx < 4096 + 3072) {
        int j = bx - 4096; in = w0; outp = Wt0; K = 1024; N = 3072; nb = j % 96; kb = j / 96; frag = true;
    } else {
        int j = bx - 7168; in = w1; outp = Wt1; K = 1024; N = 1024; nb = j % 32; kb = j / 32; frag = false;
    }
    const int bxx = nb * 32, byy = kb * 32;
    const int tx = threadIdx.x & 31, ty = threadIdx.x >> 5;
#pragma unroll
    for (int i = 0; i < 32; i += 8)
        tile[ty + i][tx] = in[(long)(byy + ty + i) * N + bxx + tx];   // tile[k_local][n_local]
    __syncthreads();
    if (frag) {
        if (threadIdx.x < 128) {
            const int nl = threadIdx.x >> 2;       // 0..31
            const int kq = threadIdx.x & 3;        // 0..3 (k octet)
            const int n = bxx + nl, k = byy + kq * 8;
            bf16x8 v;
#pragma unroll
            for (int e = 0; e < 8; ++e) v[e] = (bf16)tile[kq * 8 + e][nl];
            const long addr = (((long)(n >> 6) * 32 + (k >> 5)) * 4 + ((n >> 4) & 3)) * 512
                            + ((k >> 3) & 3) * 128 + (n & 15) * 8;
            *(bf16x8*)(outp + addr) = v;
        }
    } else {
#pragma unroll
        for (int i = 0; i < 32; i += 8)
            outp[(long)(bxx + ty + i) * K + byy + tx] = (bf16)tile[tx][ty + i];
    }
}

// ---------------- QKV GEMM: 128x192 tile, 6 waves (64x64/wave), BK=32.
// A: 3-slot LDS ring via global_load_lds (distance 2, counted vmcnt, 1 barrier/step).
// B: fragment-linear weights -> per-wave register double-buffer (distance 2), NO LDS, NO barrier. ----------------
__global__ __launch_bounds__(384, 3) void k_gemm_qkv(const bf16* __restrict__ A, const bf16* __restrict__ Bt,
                                                     const float* __restrict__ bias, bf16* __restrict__ Qs,
                                                     bf16* __restrict__ Kf, bf16* __restrict__ Vf, int Kk) {
    __shared__ __align__(16) char smem[28672];
    bf16* sA = (bf16*)smem;                // 3 slots x [128 rows][32 k], chunk-swizzled, 8 KB/slot

    const int NT = Kk >> 5;                // 32 K-steps of BK=32

    // XCD-bijective swizzle (512 % 8 == 0)
    const int bid = blockIdx.x;
    const int sid = (bid & 7) * 64 + (bid >> 3);
    const long bm = (long)(sid & 31) * 128;
    const long bn = (long)(sid >> 5) * 192;

    const int tid = threadIdx.x;
    const int w = tid >> 6, lane = tid & 63;
    const int col = lane & 15, quad = lane >> 4;
    const int wc = w % 3, wr = w / 3;
    const int wrow = wr * 64, wcol = wc * 64;

    // ---- A staging map: 512 units of 16B (unit u: row u>>2, k-octet u&3, source pre-swizzled) ----
    const int u0 = w * 64 + lane;
    const int r0s = u0 >> 2, kq0 = u0 & 3;
    const bf16* gA0 = A + (bm + r0s) * Kk + ((kq0 ^ ((r0s >> 1) & 3)) * 8);
    const int u1 = 384 + ((w & 1) * 64) + lane;    // only w<2
    const int r1s = u1 >> 2, kq1 = u1 & 3;
    const bf16* gA1 = A + (bm + r1s) * Kk + ((kq1 ^ ((r1s >> 1) & 3)) * 8);

    // ---- B fragment-linear base: strip = global 64-col index ----
    const int strip = (int)(sid >> 5) * 3 + wc;
    const bf16* wfb = Bt + (long)strip * 65536 + lane * 8;

    f32x4 acc[4][4] = {};
    bf16x8 b00, b01, b02, b03, b10, b11, b12, b13;

    // ---- prologue: stage A(0),A(1); load B(0)->b0*, B(1)->b1* ----
    // Queue (oldest first): A(0)[a], A(1)[a], B(0)[4], B(1)[4].  vmcnt(4) leaves only B(1)
    // outstanding -> A(0),A(1),B(0) complete.  Uniform for both wave classes.
    gld16(gA0, sA + u0 * 8);
    if (w < 2) gld16(gA1, sA + u1 * 8);
    gld16(gA0 + 32, sA + 4096 + u0 * 8);
    if (w < 2) gld16(gA1 + 32, sA + 4096 + u1 * 8);
    gload4(wfb, b00, b01, b02, b03);
    gload4(wfb + 2048, b10, b11, b12, b13);
    asm volatile("s_waitcnt vmcnt(4)" ::: "memory");
    __builtin_amdgcn_s_barrier();
    __builtin_amdgcn_sched_barrier(0);

#define QSTEP(T, B0, B1, B2, B3) do {                                                     \
    const int t_ = (T);                                                                   \
    const bf16* sAs = sA + (t_ % 3) * 4096;                                               \
    bf16x8 af0, af1, af2, af3;                                                            \
    { const int r_ = wrow + col;      af0 = *(const bf16x8*)(sAs + r_ * 32 + ((quad ^ ((r_ >> 1) & 3)) * 8)); } \
    { const int r_ = wrow + 16 + col; af1 = *(const bf16x8*)(sAs + r_ * 32 + ((quad ^ ((r_ >> 1) & 3)) * 8)); } \
    { const int r_ = wrow + 32 + col; af2 = *(const bf16x8*)(sAs + r_ * 32 + ((quad ^ ((r_ >> 1) & 3)) * 8)); } \
    { const int r_ = wrow + 48 + col; af3 = *(const bf16x8*)(sAs + r_ * 32 + ((quad ^ ((r_ >> 1) & 3)) * 8)); } \
    const bool pf_ = (t_ + 2 < NT);                                                       \
    if (pf_) {  /* issue A-stage(t+2) first (counts before B in vmcnt order) */           \
        bf16* dA = sA + ((t_ + 2) % 3) * 4096;                                            \
        gld16(gA0 + (t_ + 2) * 32, dA + u0 * 8);                                          \
        if (w < 2) gld16(gA1 + (t_ + 2) * 32, dA + u1 * 8);                               \
    }                                                                                     \
    __builtin_amdgcn_s_setprio(1);                                                        \
    acc[0][0] = MFMA16(af0, B0, acc[0][0]); acc[0][1] = MFMA16(af0, B1, acc[0][1]);       \
    acc[0][2] = MFMA16(af0, B2, acc[0][2]); acc[0][3] = MFMA16(af0, B3, acc[0][3]);       \
    acc[1][0] = MFMA16(af1, B0, acc[1][0]); acc[1][1] = MFMA16(af1, B1, acc[1][1]);       \
    acc[1][2] = MFMA16(af1, B2, acc[1][2]); acc[1][3] = MFMA16(af1, B3, acc[1][3]);       \
    acc[2][0] = MFMA16(af2, B0, acc[2][0]); acc[2][1] = MFMA16(af2, B1, acc[2][1]);       \
    acc[2][2] = MFMA16(af2, B2, acc[2][2]); acc[2][3] = MFMA16(af2, B3, acc[2][3]);       \
    acc[3][0] = MFMA16(af3, B0, acc[3][0]); acc[3][1] = MFMA16(af3, B1, acc[3][1]);       \
    acc[3][2] = MFMA16(af3, B2, acc[3][2]); acc[3][3] = MFMA16(af3, B3, acc[3][3]);       \
    __builtin_amdgcn_s_setprio(0);                                                        \
    if (pf_) gload4(wfb + (long)(t_ + 2) * 2048, B0, B1, B2, B3);  /* refill after use */ \
    if (t_ < NT - 2) {                                                                    \
        if (w < 2) asm volatile("s_waitcnt vmcnt(6)" ::: "memory");                       \
        else       asm volatile("s_waitcnt vmcnt(5)" ::: "memory");                       \
    } else {                                                                              \
        asm volatile("s_waitcnt vmcnt(0)" ::: "memory");                                  \
    }                                                                                     \
    __builtin_amdgcn_s_barrier();                                                         \
    __builtin_amdgcn_sched_barrier(0);                                                    \
} while (0)

#pragma unroll 1
    for (int t = 0; t < NT; t += 2) {
        QSTEP(t,     b00, b01, b02, b03);
        QSTEP(t + 1, b10, b11, b12, b13);
    }
#undef QSTEP

    // ---------------- epilogue (per-wave private; each wave's 64 cols = one head/segment) ----------------
    const long gc0 = bn + wcol;
    const int seg = (int)(gc0 >> 10);      // 0: Q, 1: K, 2: V
    float bv[4];
#pragma unroll
    for (int nt = 0; nt < 4; ++nt) bv[nt] = bias[gc0 + nt * 16 + col];

    if (seg == 0) {
#pragma unroll
        for (int nt = 0; nt < 4; ++nt) {
            const long gc = gc0 + nt * 16 + col;
#pragma unroll
            for (int mt = 0; mt < 4; ++mt) {
                const long gr = bm + wrow + mt * 16 + quad * 4;
#pragma unroll
                for (int r = 0; r < 4; ++r)
                    Qs[(gr + r) * 1024 + gc] = (bf16)((acc[mt][nt][r] + bv[nt]) * CSCALE);
            }
        }
        return;
    }

    // Per-wave scratch: 2304 elements (4608 B) per wave -> 6 x 4608 = 27648 B <= 28672 B LDS.
    // Transpose processed in TWO 32-d-column halves to fit (this was the R3/R4 overflow bug).
    bf16* myT = (bf16*)smem + w * 2304;
    const int bmi = (int)bm;
    const int b = bmi >> 11;
    const int ktw = ((bmi & 2047) >> 6) + wr;
    const int head = (int)((gc0 & 1023) >> 6);
    const int bh = b * 16 + head;

    if (seg == 1) {
        // K: per half h (d columns h*32..h*32+31): myT[seq 0..63][d-local 0..31], stride 36
#pragma unroll
        for (int h = 0; h < 2; ++h) {
#pragma unroll
            for (int mt = 0; mt < 4; ++mt)
#pragma unroll
                for (int nt2 = 0; nt2 < 2; ++nt2) {
                    const int nt = 2 * h + nt2;
#pragma unroll
                    for (int r = 0; r < 4; ++r)
                        myT[(mt * 16 + quad * 4 + r) * 36 + nt2 * 16 + col] =
                            (bf16)(acc[mt][nt][r] + bv[nt]);
                }
#pragma unroll
            for (int mtp = 0; mtp < 4; ++mtp) {
                bf16x8 ch = *(const bf16x8*)(myT + (mtp * 16 + col) * 36 + quad * 8);
                const long chunk = ((long)(bh * 32 + ktw) * 8 + mtp * 2 + h) * 64 + lane;
                *(bf16x8*)(Kf + chunk * 8) = ch;
            }
        }
    } else {
        // V: per half h (d rows h*32..h*32+31): myT[d-local 0..31][seq 0..63], stride 72
#pragma unroll
        for (int h = 0; h < 2; ++h) {
#pragma unroll
            for (int nt2 = 0; nt2 < 2; ++nt2) {
                const int nt = 2 * h + nt2;
#pragma unroll
                for (int mt = 0; mt < 4; ++mt) {
                    bf16x4 pk = { (bf16)(acc[mt][nt][0] + bv[nt]), (bf16)(acc[mt][nt][1] + bv[nt]),
                                  (bf16)(acc[mt][nt][2] + bv[nt]), (bf16)(acc[mt][nt][3] + bv[nt]) };
                    *(bf16x4*)(myT + (nt2 * 16 + col) * 72 + mt * 16 + quad * 4) = pk;
                }
            }
#pragma unroll
            for (int dt2 = 0; dt2 < 2; ++dt2) {
                const int dt = 2 * h + dt2;
#pragma unroll
                for (int ks = 0; ks < 2; ++ks) {
                    bf16x8 ch = *(const bf16x8*)(myT + (dt2 * 16 + col) * 72 + ks * 32 + quad * 8);
                    const long chunk = ((long)(bh * 32 + ktw) * 8 + dt * 2 + ks) * 64 + lane;
                    *(bf16x8*)(Vf + chunk * 8) = ch;
                }
            }
        }
    }
}

// ---------------- bf16 GEMM 64x128 tile, BK=64, XOR-swizzled (proj) ----------------
__global__ __launch_bounds__(256) void k_gemm_bt64(const bf16* __restrict__ A, const bf16* __restrict__ Bt,
                                                    const float* __restrict__ bias, float* __restrict__ Cout,
                                                    int Mm, int Nn, int Kk) {
    const int bm = blockIdx.x * 64;
    const int bn = blockIdx.y * 128;
    const int tid = threadIdx.x;
    const int w = tid >> 6, lane = tid & 63;
    const int wm = (w >> 1) * 32, wn = (w & 1) * 64;
    const int col = lane & 15, quad = lane >> 4;

    __shared__ bf16 sA[64 * 64];
    __shared__ bf16 sB[128 * 64];

    const bf16* pA[2]; bf16* lA[2];
#pragma unroll
    for (int i = 0; i < 2; i++) {
        const int c = i * 256 + w * 64 + lane;
        const int r = c >> 3, sl = (c & 7) ^ (r & 7);
        pA[i] = A + (long)(bm + r) * Kk + sl * 8;
        lA[i] = sA + i * 2048 + w * 512;
    }
    const bf16* pB[4]; bf16* lB[4];
#pragma unroll
    for (int i = 0; i < 4; i++) {
        const int c = i * 256 + w * 64 + lane;
        const int r = c >> 3, sl = (c & 7) ^ (r & 7);
        pB[i] = Bt + (long)(bn + r) * Kk + sl * 8;
        lB[i] = sB + i * 2048 + w * 512;
    }

    f32x4 acc[2][4] = {};

    for (int k0 = 0; k0 < Kk; k0 += 64) {
        __syncthreads();
#pragma unroll
        for (int i = 0; i < 2; i++) gld16(pA[i] + k0, lA[i]);
#pragma unroll
        for (int i = 0; i < 4; i++) gld16(pB[i] + k0, lB[i]);
        __syncthreads();
#pragma unroll
        for (int h = 0; h < 2; h++) {
            bf16x8 af[2], bfr[4];
#pragma unroll
            for (int mt = 0; mt < 2; mt++) {
                const int row = wm + mt * 16 + col;
                af[mt] = *(const bf16x8*)(sA + row * 64 + (((h * 4 + quad) ^ (col & 7)) * 8));
            }
#pragma unroll
            for (int nt = 0; nt < 4; nt++) {
                const int row = wn + nt * 16 + col;
                bfr[nt] = *(const bf16x8*)(sB + row * 64 + (((h * 4 + quad) ^ (col & 7)) * 8));
            }
#pragma unroll
            for (int mt = 0; mt < 2; mt++)
#pragma unroll
                for (int nt = 0; nt < 4; nt++)
                    acc[mt][nt] = MFMA16(af[mt], bfr[nt], acc[mt][nt]);
        }
    }

#pragma unroll
    for (int mt = 0; mt < 2; mt++) {
        const int gr = bm + wm + mt * 16 + quad * 4;
#pragma unroll
        for (int nt = 0; nt < 4; nt++) {
            const int gc = bn + wn + nt * 16 + col;
            const float bv = bias[gc];
#pragma unroll
            for (int r = 0; r < 4; r++)
                Cout[(long)(gr + r) * Nn + gc] = acc[mt][nt][r] + bv;
        }
    }
}

// ---------------- causal flash attention: kt-split uniform waves + flash-decode merge ----------------
__global__ __launch_bounds__(128) void k_attn(const bf16* __restrict__ Qs, const bf16* __restrict__ Kf,
                                              const bf16* __restrict__ Vf, bf16* __restrict__ out) {
    const int bh = blockIdx.x & 31;
    const int tp = blockIdx.x >> 5;           // tile pair 0..31
    const int b = bh >> 4, h = bh & 15;
    const int tid = threadIdx.x;
    const int w = tid >> 6, lane = tid & 63;
    const int col = lane & 15, quad = lane >> 4;

    __shared__ bf16 sP[2][32 * 72];
    __shared__ float M[2][64][36];            // [sel][lane][0..31 O | 32 m0 33 l0 34 m1 35 l1]
    bf16* pw = sP[w];

    const bf16* kfb = Kf + ((long)bh << 17) + lane * 8;
    const bf16* vfb = Vf + ((long)bh << 17) + lane * 8;

#pragma unroll 1
    for (int sel = 0; sel < 2; sel++) {
        const int t = sel ? 63 - tp : tp;
        const int q0 = t * 32;
        const int nkt = (t >> 1) + 1;
        const int kA = nkt >> 1;
        const int kbeg = w ? kA : 0;
        const int kend = w ? nkt : kA;

        bf16x8 bq[2][2];
#pragma unroll
        for (int qg = 0; qg < 2; qg++) {
            const bf16* qp = Qs + (long)(b * S + q0 + qg * 16 + col) * E + h * 64 + quad * 8;
            bq[qg][0] = *(const bf16x8*)(qp);
            bq[qg][1] = *(const bf16x8*)(qp + 32);
        }
        float m_[2] = { -1e30f, -1e30f }, l_[2] = { 0.f, 0.f };
        f32x4 o[2][4] = {};

#pragma unroll 1
        for (int kt = kbeg; kt < kend; kt++) {
            bf16x8 kfr[4][2], vfr[4][2];
#pragma unroll
            for (int mt = 0; mt < 4; mt++)
#pragma unroll
                for (int half = 0; half < 2; half++)
                    kfr[mt][half] = *(const bf16x8*)(kfb + ((long)(kt * 8 + mt * 2 + half) << 9));
#pragma unroll
            for (int dt = 0; dt < 4; dt++)
#pragma unroll
                for (int ks = 0; ks < 2; ks++)
                    vfr[dt][ks] = *(const bf16x8*)(vfb + ((long)(kt * 8 + dt * 2 + ks) << 9));

            f32x4 s[2][4];
#pragma unroll
            for (int mt = 0; mt < 4; mt++)
#pragma unroll
                for (int qg = 0; qg < 2; qg++) {
                    f32x4 z = {};
                    z = MFMA16(kfr[mt][0], bq[qg][0], z);
                    z = MFMA16(kfr[mt][1], bq[qg][1], z);
                    s[qg][mt] = z;
                }
            if (kt == nkt - 1) {  // diagonal tile (always in wave 1's range)
#pragma unroll
                for (int qg = 0; qg < 2; qg++) {
                    const int qrow = q0 + qg * 16 + col;
#pragma unroll
                    for (int mt = 0; mt < 4; mt++)
#pragma unroll
                        for (int r = 0; r < 4; r++)
                            if (kt * 64 + mt * 16 + quad * 4 + r > qrow) s[qg][mt][r] = -1e30f;
                }
            }
#pragma unroll
            for (int qg = 0; qg < 2; qg++) {
                float cm = -1e30f;
#pragma unroll
                for (int mt = 0; mt < 4; mt++)
#pragma unroll
                    for (int r = 0; r < 4; r++) cm = fmaxf(cm, s[qg][mt][r]);
                cm = fmaxf(cm, __shfl_xor(cm, 16));
                cm = fmaxf(cm, __shfl_xor(cm, 32));
                const float mnew = fmaxf(m_[qg], cm);
                const float alpha = __builtin_amdgcn_exp2f(m_[qg] - mnew);
                m_[qg] = mnew;
                float rs = 0.f;
#pragma unroll
                for (int mt = 0; mt < 4; mt++)
#pragma unroll
                    for (int r = 0; r < 4; r++) {
                        float pe = __builtin_amdgcn_exp2f(s[qg][mt][r] - mnew);
                        s[qg][mt][r] = pe;
                        rs += pe;
                    }
                l_[qg] = l_[qg] * alpha + rs;
#pragma unroll
                for (int dt = 0; dt < 4; dt++)
#pragma unroll
                    for (int r = 0; r < 4; r++) o[qg][dt][r] *= alpha;
#pragma unroll
                for (int mt = 0; mt < 4; mt++) {
                    bf16x4 pk = { (bf16)s[qg][mt][0], (bf16)s[qg][mt][1],
                                  (bf16)s[qg][mt][2], (bf16)s[qg][mt][3] };
                    *(bf16x4*)(pw + (qg * 16 + col) * 72 + mt * 16 + quad * 4) = pk;
                }
            }
#pragma unroll
            for (int ks = 0; ks < 2; ks++) {
                bf16x8 ap[2];
#pragma unroll
                for (int qg = 0; qg < 2; qg++)
                    ap[qg] = *(const bf16x8*)(pw + (qg * 16 + col) * 72 + ks * 32 + quad * 8);
#pragma unroll
                for (int dt = 0; dt < 4; dt++)
#pragma unroll
                    for (int qg = 0; qg < 2; qg++)
                        o[qg][dt] = MFMA16(vfr[dt][ks], ap[qg], o[qg][dt]);
            }
        }

        // finish per-lane l reduction -> replicated row sums
#pragma unroll
        for (int qg = 0; qg < 2; qg++) {
            float lt = l_[qg];
            lt += __shfl_xor(lt, 16);
            lt += __shfl_xor(lt, 32);
            l_[qg] = lt;
        }

        if (w == 0) {  // publish lower-half partials
#pragma unroll
            for (int qg = 0; qg < 2; qg++) {
#pragma unroll
                for (int dt = 0; dt < 4; dt++)
                    *(f32x4*)&M[sel][lane][qg * 16 + dt * 4] = o[qg][dt];
                M[sel][lane][32 + qg * 2] = m_[qg];
                M[sel][lane][33 + qg * 2] = l_[qg];
            }
        }
        __syncthreads();
        if (w == 1) {  // merge + output
#pragma unroll
            for (int qg = 0; qg < 2; qg++) {
                const float m0 = M[sel][lane][32 + qg * 2];
                const float l0 = M[sel][lane][33 + qg * 2];
                const float mm = fmaxf(m0, m_[qg]);
                const float a0 = __builtin_amdgcn_exp2f(m0 - mm);
                const float a1 = __builtin_amdgcn_exp2f(m_[qg] - mm);
                const float li = 1.f / (l0 * a0 + l_[qg] * a1);
                bf16* op = out + (long)(b * S + q0 + qg * 16 + col) * E + h * 64 + quad * 4;
#pragma unroll
                for (int dt = 0; dt < 4; dt++) {
                    f32x4 o0 = *(const f32x4*)&M[sel][lane][qg * 16 + dt * 4];
                    bf16x4 ov;
#pragma unroll
                    for (int r = 0; r < 4; r++)
                        ov[r] = (bf16)((o0[r] * a0 + o[qg][dt][r] * a1) * li);
                    *(bf16x4*)(op + dt * 16) = ov;
                }
            }
        }
    }
}

extern "C" void kernel_launch(void* const* d_in, const int* in_sizes, int n_in,
                              void* d_out, int out_size, void* d_ws, size_t ws_size,
                              hipStream_t stream) {
    const float* hs = (const float*)d_in[0];   // [2,2048,1024]
    const float* w0 = (const float*)d_in[1];   // [1024,3072]
    const float* b0 = (const float*)d_in[2];   // [3072]
    const float* w1 = (const float*)d_in[3];   // [1024,1024]
    const float* b1 = (const float*)d_in[4];   // [1024]
    float* outp = (float*)d_out;               // [2,2048,1024] fp32

    char* ws = (char*)d_ws;
    bf16* A0    = (bf16*)(ws);                   // 8 MB
    bf16* Wt0   = (bf16*)(ws + 8388608);         // 6 MB  (fragment-linear)
    bf16* Wt1   = (bf16*)(ws + 14680064);        // 2 MB
    bf16* Qs    = (bf16*)(ws + 16777216);        // 8 MB  [4096][1024] scaled Q
    bf16* Kf    = (bf16*)(ws + 25165824);        // 8 MB  fragment-linear K
    bf16* Vf    = (bf16*)(ws + 33554432);        // 8 MB  fragment-linear V^T
    bf16* attnO = (bf16*)(ws + 41943040);        // 8 MB

    k_prep<<<8192, 256, 0, stream>>>(hs, w0, w1, A0, Wt0, Wt1);
    k_gemm_qkv<<<512, 384, 0, stream>>>(A0, Wt0, b0, Qs, Kf, Vf, 1024);
    k_attn<<<1024, 128, 0, stream>>>(Qs, Kf, Vf, attnO);
    k_gemm_bt64<<<dim3(64, 8), 256, 0, stream>>>(attnO, Wt1, b1, outp, 4096, 1024, 1024);
}